// Round 2
// baseline (62.558 us; speedup 1.0000x reference)
//
#include <hip/hip_runtime.h>
#include <stdint.h>

#define BATCH 32768
#define NM 64

struct Keys { uint32_t k[8]; };

// Threefry-2x32, 20 rounds — matches jax._src.prng.threefry2x32 exactly.
__host__ __device__ inline void threefry2x32(uint32_t k0, uint32_t k1,
                                             uint32_t x0, uint32_t x1,
                                             uint32_t* o0, uint32_t* o1) {
  uint32_t k2 = k0 ^ k1 ^ 0x1BD11BDAu;
  x0 += k0; x1 += k1;
#define TF_RND(r) { x0 += x1; x1 = (x1 << (r)) | (x1 >> (32 - (r))); x1 ^= x0; }
  TF_RND(13) TF_RND(15) TF_RND(26) TF_RND(6)
  x0 += k1; x1 += k2 + 1u;
  TF_RND(17) TF_RND(29) TF_RND(16) TF_RND(24)
  x0 += k2; x1 += k0 + 2u;
  TF_RND(13) TF_RND(15) TF_RND(26) TF_RND(6)
  x0 += k0; x1 += k1 + 3u;
  TF_RND(17) TF_RND(29) TF_RND(16) TF_RND(24)
  x0 += k1; x1 += k2 + 4u;
  TF_RND(13) TF_RND(15) TF_RND(26) TF_RND(6)
  x0 += k2; x1 += k0 + 5u;
#undef TF_RND
  *o0 = x0; *o1 = x1;
}

// bits -> uniform[1e-10,1) -> gumbel, matching jax._src.random._uniform:
// float_bits=(bits>>9)|0x3F800000; f=bitcast-1.0; u=max(1e-10, f*1.0f+1e-10)
__device__ inline float gumbel_g(uint32_t bits) {
  float f = __uint_as_float((bits >> 9) | 0x3F800000u) - 1.0f;
  float u = fmaxf(1e-10f, f + 1e-10f);
  return -logf(-logf(u));
}

__device__ inline float tanh_fast(float x) {
  // 1 - 2/(e^{2x}+1); abs err ~1e-7, tolerance here is ~1e-2
  float e = __expf(2.0f * x);
#if __has_builtin(__builtin_amdgcn_rcpf)
  float r = __builtin_amdgcn_rcpf(e + 1.0f);
#else
  float r = 1.0f / (e + 1.0f);
#endif
  return fmaf(-2.0f, r, 1.0f);
}

// One fused kernel: block = 256 threads handles 64 batch rows (b0..b0+63).
// Phase 1: gumbel-argmax winners (thread per (b,d,j), top-2 for exclusion)
// Phase 2: sparse MLP eval, one (b,d,j) row per wave iteration (coalesced)
// Phase 3: out0 combine + exact one-hot gate writes (coalesced float4)
__global__ __launch_bounds__(256) void k_fused(Keys keys,
    const float* __restrict__ X,   const float* __restrict__ W1,
    const float* __restrict__ b1v, const float* __restrict__ W2,
    const float* __restrict__ b2v, const float* __restrict__ routers,
    const float* __restrict__ coef, const float* __restrict__ cp,
    float* __restrict__ out0, float4* __restrict__ gates) {
  __shared__ float basev[2][NM];
  __shared__ float xlds[64 * 2];
  __shared__ float part[256];
  __shared__ uint8_t wlds[4][64];

  const int t = threadIdx.x;
  const int b0 = blockIdx.x * 64;

  if (t < 128) {
    basev[t >> 6][t & 63] = routers[t] + cp[t & 63];
    xlds[t] = X[b0 * 2 + t];
  }
  __syncthreads();

  // ---- phase 1: per-(b,d,j) gumbel argmax with top-2 tracking ----
  const int bl = t >> 2, d = (t >> 1) & 1, j = t & 1;
  const int dj = d * 2 + j;
  const uint32_t k0 = keys.k[dj * 2 + 0], k1 = keys.k[dj * 2 + 1];
  const uint32_t ibase = (uint32_t)(b0 + bl) * NM;  // row-major (B,M) index
  float best = -1e30f, second = -1e30f;
  int bi = 0, si = 0;
#pragma unroll 8
  for (int m = 0; m < NM; ++m) {
    uint32_t o0, o1;
    // partitionable threefry: counter=(hi,lo) of 64-bit index; bits = o0^o1
    threefry2x32(k0, k1, 0u, ibase + (uint32_t)m, &o0, &o1);
    float z = basev[d][m] + gumbel_g(o0 ^ o1);
    if (z > best)        { second = best; si = bi; best = z; bi = m; }
    else if (z > second) { second = z; si = m; }
  }
  // j=1 excludes j=0's winner (mask=-1e9*one-hot can never win);
  // partner (j=0) is the adjacent lane.
  const int w0p = __shfl_xor(bi, 1);
  const int w = (j == 0) ? bi : ((bi == w0p) ? si : bi);
  wlds[dj][bl] = (uint8_t)w;
  __syncthreads();

  // ---- phase 2: sparse MLP, one row per wave iter; expert idx wave-uniform ----
  const int wv = t >> 6, lane = t & 63;
  for (int i = 0; i < 64; ++i) {
    const int r = wv * 64 + i;              // row = bl*4 + d*2 + j
    const int rbl = r >> 2, rdj = r & 3;
    int rw = wlds[rdj][rbl];
    rw = __builtin_amdgcn_readfirstlane(rw);   // SGPR base -> coalesced loads
    const float xa = xlds[rbl * 2 + 0], xb = xlds[rbl * 2 + 1];
    const float2 a0 = *(const float2*)(W1 + rw * 256 + lane * 2);        // W1[w][0]
    const float2 a1 = *(const float2*)(W1 + rw * 256 + 128 + lane * 2);  // W1[w][1]
    const float2 bb = *(const float2*)(b1v + rw * 128 + lane * 2);
    const float2 ww = *(const float2*)(W2 + rw * 128 + lane * 2);
    float h0 = fmaf(xb, a1.x, fmaf(xa, a0.x, bb.x));
    float h1 = fmaf(xb, a1.y, fmaf(xa, a0.y, bb.y));
    float s = fmaf(tanh_fast(h1), ww.y, tanh_fast(h0) * ww.x);
#pragma unroll
    for (int sft = 1; sft < 64; sft <<= 1) s += __shfl_xor(s, sft);
    if (lane == 0) part[r] = coef[rdj * NM + rw] * (s + b2v[rw]);
  }
  __syncthreads();

  // ---- out0 combine: fl(term_j0 + term_j1), matching reference order ----
  if (t < 128) {
    const int obl = t >> 1, od = t & 1;
    const float p0 = part[obl * 4 + od * 2 + 0];
    const float p1 = part[obl * 4 + od * 2 + 1];
    out0[(b0 + obl) * 2 + od] = p0 + p1;
  }

  // ---- phase 3: exact one-hot gates (S,K,B,M), coalesced float4 stores ----
#pragma unroll
  for (int it = 0; it < 16; ++it) {
    const int idx = it * 256 + t;           // 0..4095 = dj(4) x bl(64) x q(16)
    const int gdj = idx >> 10;
    const int gbl = (idx >> 4) & 63;
    const int q = idx & 15;
    const int gw = wlds[gdj][gbl];
    const int m0 = q * 4;
    float4 v;
    v.x = (m0 + 0 == gw) ? 1.0f : 0.0f;
    v.y = (m0 + 1 == gw) ? 1.0f : 0.0f;
    v.z = (m0 + 2 == gw) ? 1.0f : 0.0f;
    v.w = (m0 + 3 == gw) ? 1.0f : 0.0f;
    gates[(gdj * BATCH + b0 + gbl) * 16 + q] = v;
  }
}

extern "C" void kernel_launch(void* const* d_in, const int* in_sizes, int n_in,
                              void* d_out, int out_size, void* d_ws, size_t ws_size,
                              hipStream_t stream) {
  const float* X       = (const float*)d_in[0];
  const float* W1      = (const float*)d_in[1];
  const float* b1v     = (const float*)d_in[2];
  const float* W2      = (const float*)d_in[3];
  const float* b2v     = (const float*)d_in[4];
  const float* routers = (const float*)d_in[5];
  const float* coef    = (const float*)d_in[6];
  const float* cp      = (const float*)d_in[7];
  float* out0  = (float*)d_out;
  float* gates = out0 + BATCH * 2;          // outputs concatenated flat

  // fold_in(key(42), dj) = threefry2x32((0,42), (0,dj))
  Keys keys;
  for (uint32_t dj = 0; dj < 4; ++dj) {
    uint32_t o0, o1;
    threefry2x32(0u, 42u, 0u, dj, &o0, &o1);
    keys.k[dj * 2 + 0] = o0;
    keys.k[dj * 2 + 1] = o1;
  }

  k_fused<<<dim3(BATCH / 64), dim3(256), 0, stream>>>(
      keys, X, W1, b1v, W2, b2v, routers, coef, cp, out0, (float4*)gates);
}

// Round 3
// 47.158 us; speedup vs baseline: 1.3266x; 1.3266x over previous
//
#include <hip/hip_runtime.h>
#include <stdint.h>

#define BATCH 32768
#define NM 64

struct Keys { uint32_t k[8]; };

// Threefry-2x32, 20 rounds — matches jax._src.prng.threefry2x32 exactly.
__host__ __device__ inline void threefry2x32(uint32_t k0, uint32_t k1,
                                             uint32_t x0, uint32_t x1,
                                             uint32_t* o0, uint32_t* o1) {
  uint32_t k2 = k0 ^ k1 ^ 0x1BD11BDAu;
  x0 += k0; x1 += k1;
#define TF_RND(r) { x0 += x1; x1 = (x1 << (r)) | (x1 >> (32 - (r))); x1 ^= x0; }
  TF_RND(13) TF_RND(15) TF_RND(26) TF_RND(6)
  x0 += k1; x1 += k2 + 1u;
  TF_RND(17) TF_RND(29) TF_RND(16) TF_RND(24)
  x0 += k2; x1 += k0 + 2u;
  TF_RND(13) TF_RND(15) TF_RND(26) TF_RND(6)
  x0 += k0; x1 += k1 + 3u;
  TF_RND(17) TF_RND(29) TF_RND(16) TF_RND(24)
  x0 += k1; x1 += k2 + 4u;
  TF_RND(13) TF_RND(15) TF_RND(26) TF_RND(6)
  x0 += k2; x1 += k0 + 5u;
#undef TF_RND
  *o0 = x0; *o1 = x1;
}

// bits -> uniform[1e-10,1) -> gumbel, matching jax._src.random._uniform bit-exactly.
// DO NOT change this math: current build has 0 argmax flips vs reference.
__device__ inline float gumbel_g(uint32_t bits) {
  float f = __uint_as_float((bits >> 9) | 0x3F800000u) - 1.0f;
  float u = fmaxf(1e-10f, f + 1e-10f);
  return -logf(-logf(u));
}

__device__ inline float tanh_fast(float x) {
  float e = __expf(2.0f * x);
#if __has_builtin(__builtin_amdgcn_rcpf)
  float r = __builtin_amdgcn_rcpf(e + 1.0f);
#else
  float r = 1.0f / (e + 1.0f);
#endif
  return fmaf(-2.0f, r, 1.0f);
}

// Block = 256 threads, 16 batch rows. 2048 blocks -> 32 waves/CU (occupancy fix).
// Phase 1: 4 threads per (b,d,j); 16 draws each; top-2 shfl merge (first-max order)
// Phase 2: sparse MLP, one (b,d,j) row per wave iteration (16 iters/wave)
// Phase 3: out0 combine + exact one-hot gate writes (coalesced float4)
__global__ __launch_bounds__(256) void k_fused(Keys keys,
    const float* __restrict__ X,   const float* __restrict__ W1,
    const float* __restrict__ b1v, const float* __restrict__ W2,
    const float* __restrict__ b2v, const float* __restrict__ routers,
    const float* __restrict__ coef, const float* __restrict__ cp,
    float* __restrict__ out0, float4* __restrict__ gates) {
  __shared__ float basev[2][NM];
  __shared__ float xlds[16 * 2];
  __shared__ float part[64];
  __shared__ uint8_t wlds[4][16];

  const int t = threadIdx.x;
  const int b0 = blockIdx.x * 16;

  if (t < 128) basev[t >> 6][t & 63] = routers[t] + cp[t & 63];
  if (t < 32)  xlds[t] = X[b0 * 2 + t];
  __syncthreads();

  // ---- phase 1 ----
  const int g = t >> 2, sub = t & 3;        // g = bl*4 + d*2 + j
  const int dj = g & 3, bl = g >> 2;
  const uint32_t k0 = keys.k[dj * 2 + 0], k1 = keys.k[dj * 2 + 1];
  const uint32_t ibase = (uint32_t)(b0 + bl) * NM + (uint32_t)sub * 16;
  const float* bv = &basev[dj >> 1][sub * 16];
  float best = -1e30f, second = -1e30f;
  int bi = 0, si = 0;
#pragma unroll 4
  for (int mm = 0; mm < 16; ++mm) {
    uint32_t o0, o1;
    threefry2x32(k0, k1, 0u, ibase + (uint32_t)mm, &o0, &o1);
    float z = bv[mm] + gumbel_g(o0 ^ o1);
    int m = sub * 16 + mm;
    if (z > best)        { second = best; si = bi; best = z; bi = m; }
    else if (z > second) { second = z; si = m; }
  }
  // merge top-2 across the 4 sub-lanes; comparator (v> || (v== && i<)) keeps
  // jnp.argmax first-max semantics exactly.
#pragma unroll
  for (int dlt = 1; dlt <= 2; dlt <<= 1) {
    float ob = __shfl_xor(best, dlt);  int obi = __shfl_xor(bi, dlt);
    float os = __shfl_xor(second, dlt); int osi = __shfl_xor(si, dlt);
    bool selfWins = (best > ob) || (best == ob && bi < obi);
    if (selfWins) {
      if (ob > second || (ob == second && obi < si)) { second = ob; si = obi; }
    } else {
      if (best > os || (best == os && bi < osi)) { second = best; si = bi; }
      else { second = os; si = osi; }
      best = ob; bi = obi;
    }
  }
  // j=1 excludes j=0's winner; partner group is g^1 (4 lanes away)
  const int w0p = __shfl_xor(bi, 4);
  const int w = ((g & 1) == 0) ? bi : ((bi == w0p) ? si : bi);
  if (sub == 0) wlds[dj][bl] = (uint8_t)w;
  __syncthreads();

  // ---- phase 2: one row per wave iter; expert idx wave-uniform ----
  const int wv = t >> 6, lane = t & 63;
  for (int i = 0; i < 16; ++i) {
    const int r = wv * 16 + i;              // row = rbl*4 + rdj
    const int rbl = r >> 2, rdj = r & 3;
    int rw = wlds[rdj][rbl];
    rw = __builtin_amdgcn_readfirstlane(rw);
    const float xa = xlds[rbl * 2 + 0], xb = xlds[rbl * 2 + 1];
    const float2 a0 = *(const float2*)(W1 + rw * 256 + lane * 2);
    const float2 a1 = *(const float2*)(W1 + rw * 256 + 128 + lane * 2);
    const float2 bb = *(const float2*)(b1v + rw * 128 + lane * 2);
    const float2 ww = *(const float2*)(W2 + rw * 128 + lane * 2);
    float h0 = fmaf(xb, a1.x, fmaf(xa, a0.x, bb.x));
    float h1 = fmaf(xb, a1.y, fmaf(xa, a0.y, bb.y));
    float s = fmaf(tanh_fast(h1), ww.y, tanh_fast(h0) * ww.x);
#pragma unroll
    for (int sft = 1; sft < 64; sft <<= 1) s += __shfl_xor(s, sft);
    if (lane == 0) part[r] = coef[rdj * NM + rw] * (s + b2v[rw]);
  }
  __syncthreads();

  // ---- out0 combine ----
  if (t < 32) {
    const int obl = t >> 1, od = t & 1;
    out0[(b0 + obl) * 2 + od] =
        part[obl * 4 + od * 2 + 0] + part[obl * 4 + od * 2 + 1];
  }

  // ---- phase 3: exact one-hot gates (S,K,B,M), coalesced float4 ----
#pragma unroll
  for (int it = 0; it < 4; ++it) {          // it = dj
    const int gb = t >> 4, q = t & 15;
    const int gw = wlds[it][gb];
    const int m0 = q * 4;
    float4 v;
    v.x = (m0 + 0 == gw) ? 1.0f : 0.0f;
    v.y = (m0 + 1 == gw) ? 1.0f : 0.0f;
    v.z = (m0 + 2 == gw) ? 1.0f : 0.0f;
    v.w = (m0 + 3 == gw) ? 1.0f : 0.0f;
    gates[(it * BATCH + b0 + gb) * 16 + q] = v;
  }
}

extern "C" void kernel_launch(void* const* d_in, const int* in_sizes, int n_in,
                              void* d_out, int out_size, void* d_ws, size_t ws_size,
                              hipStream_t stream) {
  const float* X       = (const float*)d_in[0];
  const float* W1      = (const float*)d_in[1];
  const float* b1v     = (const float*)d_in[2];
  const float* W2      = (const float*)d_in[3];
  const float* b2v     = (const float*)d_in[4];
  const float* routers = (const float*)d_in[5];
  const float* coef    = (const float*)d_in[6];
  const float* cp      = (const float*)d_in[7];
  float* out0  = (float*)d_out;
  float* gates = out0 + BATCH * 2;

  Keys keys;
  for (uint32_t dj = 0; dj < 4; ++dj) {
    uint32_t o0, o1;
    threefry2x32(0u, 42u, 0u, dj, &o0, &o1);
    keys.k[dj * 2 + 0] = o0;
    keys.k[dj * 2 + 1] = o1;
  }

  k_fused<<<dim3(BATCH / 16), dim3(256), 0, stream>>>(
      keys, X, W1, b1v, W2, b2v, routers, coef, cp, out0, (float4*)gates);
}

// Round 4
// 35.689 us; speedup vs baseline: 1.7529x; 1.3213x over previous
//
#include <hip/hip_runtime.h>
#include <stdint.h>

#define BATCH 32768
#define NM 64

struct Keys { uint32_t k[8]; };

// Threefry-2x32, 20 rounds — matches jax._src.prng.threefry2x32 exactly.
__host__ __device__ inline void threefry2x32(uint32_t k0, uint32_t k1,
                                             uint32_t x0, uint32_t x1,
                                             uint32_t* o0, uint32_t* o1) {
  uint32_t k2 = k0 ^ k1 ^ 0x1BD11BDAu;
  x0 += k0; x1 += k1;
#define TF_RND(r) { x0 += x1; x1 = (x1 << (r)) | (x1 >> (32 - (r))); x1 ^= x0; }
  TF_RND(13) TF_RND(15) TF_RND(26) TF_RND(6)
  x0 += k1; x1 += k2 + 1u;
  TF_RND(17) TF_RND(29) TF_RND(16) TF_RND(24)
  x0 += k2; x1 += k0 + 2u;
  TF_RND(13) TF_RND(15) TF_RND(26) TF_RND(6)
  x0 += k0; x1 += k1 + 3u;
  TF_RND(17) TF_RND(29) TF_RND(16) TF_RND(24)
  x0 += k1; x1 += k2 + 4u;
  TF_RND(13) TF_RND(15) TF_RND(26) TF_RND(6)
  x0 += k2; x1 += k0 + 5u;
#undef TF_RND
  *o0 = x0; *o1 = x1;
}

// bits -> uniform[1e-10,1) -> gumbel, matching jax._src.random._uniform bit-exactly.
// DO NOT change this math: verified 0 argmax flips vs reference.
__device__ inline float gumbel_g(uint32_t bits) {
  float f = __uint_as_float((bits >> 9) | 0x3F800000u) - 1.0f;
  float u = fmaxf(1e-10f, f + 1e-10f);
  return -logf(-logf(u));
}

__device__ inline float tanh_fast(float x) {
  float e = __expf(2.0f * x);
#if __has_builtin(__builtin_amdgcn_rcpf)
  float r = __builtin_amdgcn_rcpf(e + 1.0f);
#else
  float r = 1.0f / (e + 1.0f);
#endif
  return fmaf(-2.0f, r, 1.0f);
}

// Block = 256 threads, 16 batch rows, 2048 blocks (8 blocks/CU).
// Phase 1: 4 threads per (b,d,j); 16 draws each (base vals hoisted to VGPR);
//          top-2 shfl merge preserving jnp.argmax first-max semantics.
// Gates:   emitted right after winners (posted writes drain under phase 2).
// Phase 2: sparse MLP, one row per 16-LANE GROUP (4 rows/wave in flight,
//          4 iters, 4-step butterfly) — short dependence chains.
__global__ __launch_bounds__(256) void k_fused(Keys keys,
    const float* __restrict__ X,   const float* __restrict__ W1,
    const float* __restrict__ b1v, const float* __restrict__ W2,
    const float* __restrict__ b2v, const float* __restrict__ routers,
    const float* __restrict__ coef, const float* __restrict__ cp,
    float* __restrict__ out0, float4* __restrict__ gates) {
  __shared__ float basev[2][NM];
  __shared__ float xlds[16 * 2];
  __shared__ float part[64];
  __shared__ uint8_t wlds[4][16];

  const int t = threadIdx.x;
  const int b0 = blockIdx.x * 16;

  if (t < 128) basev[t >> 6][t & 63] = routers[t] + cp[t & 63];
  if (t < 32)  xlds[t] = X[b0 * 2 + t];
  __syncthreads();

  // ---- phase 1 (verified numerics — unchanged z math) ----
  const int g = t >> 2, sub = t & 3;        // g = bl*4 + d*2 + j
  const int dj = g & 3, bl = g >> 2;
  const uint32_t k0 = keys.k[dj * 2 + 0], k1 = keys.k[dj * 2 + 1];
  const uint32_t ibase = (uint32_t)(b0 + bl) * NM + (uint32_t)sub * 16;
  // hoist the 16 base values into registers (4x ds_read_b128)
  const float4* bq = (const float4*)&basev[dj >> 1][sub * 16];
  const float4 q0 = bq[0], q1 = bq[1], q2 = bq[2], q3 = bq[3];
  const float bvr[16] = {q0.x, q0.y, q0.z, q0.w, q1.x, q1.y, q1.z, q1.w,
                         q2.x, q2.y, q2.z, q2.w, q3.x, q3.y, q3.z, q3.w};
  float best = -1e30f, second = -1e30f;
  int bi = 0, si = 0;
#pragma unroll
  for (int mm = 0; mm < 16; ++mm) {
    uint32_t o0, o1;
    threefry2x32(k0, k1, 0u, ibase + (uint32_t)mm, &o0, &o1);
    float z = bvr[mm] + gumbel_g(o0 ^ o1);
    int m = sub * 16 + mm;
    if (z > best)        { second = best; si = bi; best = z; bi = m; }
    else if (z > second) { second = z; si = m; }
  }
  // top-2 merge across 4 sub-lanes; comparator (v> || (v== && i<)) == first-max
#pragma unroll
  for (int dlt = 1; dlt <= 2; dlt <<= 1) {
    float ob = __shfl_xor(best, dlt);  int obi = __shfl_xor(bi, dlt);
    float os = __shfl_xor(second, dlt); int osi = __shfl_xor(si, dlt);
    bool selfWins = (best > ob) || (best == ob && bi < obi);
    if (selfWins) {
      if (ob > second || (ob == second && obi < si)) { second = ob; si = obi; }
    } else {
      if (best > os || (best == os && bi < osi)) { second = best; si = bi; }
      else { second = os; si = osi; }
      best = ob; bi = obi;
    }
  }
  const int w0p = __shfl_xor(bi, 4);        // partner (j=0) group is g^1
  const int w = ((g & 1) == 0) ? bi : ((bi == w0p) ? si : bi);
  if (sub == 0) wlds[dj][bl] = (uint8_t)w;
  __syncthreads();

  // ---- gates first: depend only on winners; stores drain under phase 2 ----
  {
    const int gb = t >> 4, q = t & 15;
    const int m0 = q * 4;
#pragma unroll
    for (int it = 0; it < 4; ++it) {
      const int gw = wlds[it][gb];
      float4 v;
      v.x = (m0 + 0 == gw) ? 1.0f : 0.0f;
      v.y = (m0 + 1 == gw) ? 1.0f : 0.0f;
      v.z = (m0 + 2 == gw) ? 1.0f : 0.0f;
      v.w = (m0 + 3 == gw) ? 1.0f : 0.0f;
      gates[(it * BATCH + b0 + gb) * 16 + q] = v;
    }
  }

  // ---- phase 2: one row per 16-lane group ----
  const int wv = t >> 6, lane = t & 63;
  const int grp = lane >> 4, sl = lane & 15;
#pragma unroll
  for (int i = 0; i < 4; ++i) {
    const int r = wv * 16 + i * 4 + grp;    // row = rbl*4 + rdj
    const int rbl = r >> 2, rdj = r & 3;
    const int rw = wlds[rdj][rbl];
    const float xa = xlds[rbl * 2 + 0], xb = xlds[rbl * 2 + 1];
    const float4* A0 = (const float4*)(W1 + rw * 256 + sl * 8);
    const float4* A1 = (const float4*)(W1 + rw * 256 + 128 + sl * 8);
    const float4* B1 = (const float4*)(b1v + rw * 128 + sl * 8);
    const float4* WW = (const float4*)(W2 + rw * 128 + sl * 8);
    const float4 a0a = A0[0], a0b = A0[1];
    const float4 a1a = A1[0], a1b = A1[1];
    const float4 b1a = B1[0], b1b = B1[1];
    float h0 = fmaf(xb, a1a.x, fmaf(xa, a0a.x, b1a.x));
    float h1 = fmaf(xb, a1a.y, fmaf(xa, a0a.y, b1a.y));
    float h2 = fmaf(xb, a1a.z, fmaf(xa, a0a.z, b1a.z));
    float h3 = fmaf(xb, a1a.w, fmaf(xa, a0a.w, b1a.w));
    float h4 = fmaf(xb, a1b.x, fmaf(xa, a0b.x, b1b.x));
    float h5 = fmaf(xb, a1b.y, fmaf(xa, a0b.y, b1b.y));
    float h6 = fmaf(xb, a1b.z, fmaf(xa, a0b.z, b1b.z));
    float h7 = fmaf(xb, a1b.w, fmaf(xa, a0b.w, b1b.w));
    const float4 w2a = WW[0], w2b = WW[1];
    float s = tanh_fast(h0) * w2a.x;
    s = fmaf(tanh_fast(h1), w2a.y, s);
    s = fmaf(tanh_fast(h2), w2a.z, s);
    s = fmaf(tanh_fast(h3), w2a.w, s);
    s = fmaf(tanh_fast(h4), w2b.x, s);
    s = fmaf(tanh_fast(h5), w2b.y, s);
    s = fmaf(tanh_fast(h6), w2b.z, s);
    s = fmaf(tanh_fast(h7), w2b.w, s);
#pragma unroll
    for (int sft = 1; sft < 16; sft <<= 1) s += __shfl_xor(s, sft);
    if (sl == 0) part[r] = coef[rdj * NM + rw] * (s + b2v[rw]);
  }
  __syncthreads();

  // ---- out0 combine: fl(term_j0 + term_j1), matching reference order ----
  if (t < 32) {
    const int obl = t >> 1, od = t & 1;
    out0[(b0 + obl) * 2 + od] =
        part[obl * 4 + od * 2 + 0] + part[obl * 4 + od * 2 + 1];
  }
}

extern "C" void kernel_launch(void* const* d_in, const int* in_sizes, int n_in,
                              void* d_out, int out_size, void* d_ws, size_t ws_size,
                              hipStream_t stream) {
  const float* X       = (const float*)d_in[0];
  const float* W1      = (const float*)d_in[1];
  const float* b1v     = (const float*)d_in[2];
  const float* W2      = (const float*)d_in[3];
  const float* b2v     = (const float*)d_in[4];
  const float* routers = (const float*)d_in[5];
  const float* coef    = (const float*)d_in[6];
  const float* cp      = (const float*)d_in[7];
  float* out0  = (float*)d_out;
  float* gates = out0 + BATCH * 2;

  Keys keys;
  for (uint32_t dj = 0; dj < 4; ++dj) {
    uint32_t o0, o1;
    threefry2x32(0u, 42u, 0u, dj, &o0, &o1);
    keys.k[dj * 2 + 0] = o0;
    keys.k[dj * 2 + 1] = o1;
  }

  k_fused<<<dim3(BATCH / 16), dim3(256), 0, stream>>>(
      keys, X, W1, b1v, W2, b2v, routers, coef, cp, out0, (float4*)gates);
}